// Round 1
// baseline (205.499 us; speedup 1.0000x reference)
//
#include <hip/hip_runtime.h>

// CliffordLayerNorm: per-256-float block, per-grade (popcount) layernorm.
// One wave handles 4 MV blocks (16 lanes each); lane l of a group holds the
// 16 elements m = 64k + 4l + j (k,j in 0..3). popcount(m) = pc(k)+pc(l)+pc(j),
// so each lane's elements occupy relative grades 0..4 above base pc(l).
// Per-grade sums are reduced with a "Pascal" butterfly over the 4 lane bits:
// arrays stay aligned to the grade base of the remaining unreduced bits and
// grow 5 -> 9 entries.

static __device__ __forceinline__ float shx(float v, int m) {
    return __shfl_xor(v, m, 64);
}

template <int STEP>
static __device__ __forceinline__ void pascal_step(float (&s)[9], float (&q)[9], int l) {
    constexpr int BM = 1 << STEP;
    constexpr int L  = 5 + STEP;  // array length before this merge
    const bool hi = (l & BM) != 0;
    float ts[9], tq[9];
#pragma unroll
    for (int j = 0; j < L; ++j) { ts[j] = shx(s[j], BM); tq[j] = shx(q[j], BM); }
    float ns[9], nq[9];
#pragma unroll
    for (int j = 0; j <= L; ++j) {
        float slo = (j < L) ? (hi ? ts[j] : s[j]) : 0.0f;
        float shi = (j > 0) ? (hi ? s[j - 1] : ts[j - 1]) : 0.0f;
        ns[j] = slo + shi;
        float qlo = (j < L) ? (hi ? tq[j] : q[j]) : 0.0f;
        float qhi = (j > 0) ? (hi ? q[j - 1] : tq[j - 1]) : 0.0f;
        nq[j] = qlo + qhi;
    }
#pragma unroll
    for (int j = 0; j <= L; ++j) { s[j] = ns[j]; q[j] = nq[j]; }
}

__global__ __launch_bounds__(256) void cliff_ln_kernel(
    const float* __restrict__ x, const float* __restrict__ w,
    const float* __restrict__ b, float* __restrict__ out, int nblk)
{
    const int lane = threadIdx.x & 63;
    const int grp  = lane >> 4;   // which of the 4 blocks this wave handles
    const int l    = lane & 15;   // lane within the 16-lane group
    const int p    = __popc(l);   // grade base of this lane's elements
    const int wave_id     = (blockIdx.x * blockDim.x + threadIdx.x) >> 6;
    const int total_waves = (gridDim.x * blockDim.x) >> 6;

    // weight/bias are tiny and uniform: hoist (compiler emits s_loads)
    float wg[9], bg[9];
#pragma unroll
    for (int g = 0; g < 9; ++g) { wg[g] = w[g]; bg[g] = b[g]; }

    const float invc[9] = {1.0f, 0.125f, 1.0f/28.0f, 1.0f/56.0f, 1.0f/70.0f,
                           1.0f/56.0f, 1.0f/28.0f, 0.125f, 1.0f};

    const int nquad = nblk >> 2;
    for (int quad = wave_id; quad < nquad; quad += total_waves) {
        const int blk = (quad << 2) + grp;
        const float4* xb = reinterpret_cast<const float4*>(x) + (size_t)blk * 64;
        // element m = 64k + 4l + j  ->  float4 index 16k + l
        float4 xv0 = xb[ 0 + l];
        float4 xv1 = xb[16 + l];
        float4 xv2 = xb[32 + l];
        float4 xv3 = xb[48 + l];

        float s[9], q[9];
#pragma unroll
        for (int j = 0; j < 9; ++j) { s[j] = 0.0f; q[j] = 0.0f; }

        // relative grade of component j within a float4 = pc(j) = {0,1,1,2};
        // plus pc(k) for the k-th float4 = {0,1,1,2}
#define ACC1(v, r) { s[r] += (v); q[r] = fmaf((v), (v), q[r]); }
#define ACC4(vv, pk) { ACC1((vv).x, (pk)+0) ACC1((vv).y, (pk)+1) \
                       ACC1((vv).z, (pk)+1) ACC1((vv).w, (pk)+2) }
        ACC4(xv0, 0) ACC4(xv1, 1) ACC4(xv2, 1) ACC4(xv3, 2)
#undef ACC4
#undef ACC1

        pascal_step<0>(s, q, l);
        pascal_step<1>(s, q, l);
        pascal_step<2>(s, q, l);
        pascal_step<3>(s, q, l);
        // now s[g], q[g] = per-grade sum / sum-of-squares for this group's block

        float scl[9], sft[9];
#pragma unroll
        for (int g = 0; g < 9; ++g) {
            float mean = s[g] * invc[g];
            float var  = fmaf(-mean, mean, q[g] * invc[g]);
            var = fmaxf(var, 0.0f);
            float inv = rsqrtf(var + 1e-5f);
            float sc  = inv * wg[g];
            scl[g] = sc;
            sft[g] = fmaf(-mean, sc, bg[g]);
        }

        // shift arrays down by p (a[j] <- a[j+p]), p in 0..4, branchless.
        // p==4 excludes p&2/p&1, so the windows below are sufficient.
        const bool p4 = (p & 4) != 0, p2 = (p & 2) != 0, p1 = (p & 1) != 0;
#pragma unroll
        for (int j = 0; j < 5; ++j) { scl[j] = p4 ? scl[j+4] : scl[j];
                                      sft[j] = p4 ? sft[j+4] : sft[j]; }
#pragma unroll
        for (int j = 0; j < 6; ++j) { scl[j] = p2 ? scl[j+2] : scl[j];
                                      sft[j] = p2 ? sft[j+2] : sft[j]; }
#pragma unroll
        for (int j = 0; j < 5; ++j) { scl[j] = p1 ? scl[j+1] : scl[j];
                                      sft[j] = p1 ? sft[j+1] : sft[j]; }
        // scl[r]/sft[r] now correspond to absolute grade p + r

        float4* ob = reinterpret_cast<float4*>(out) + (size_t)blk * 64;
#define OUT4(vv, pk, idx) { float4 o; \
        o.x = fmaf((vv).x, scl[(pk)+0], sft[(pk)+0]); \
        o.y = fmaf((vv).y, scl[(pk)+1], sft[(pk)+1]); \
        o.z = fmaf((vv).z, scl[(pk)+1], sft[(pk)+1]); \
        o.w = fmaf((vv).w, scl[(pk)+2], sft[(pk)+2]); \
        ob[(idx) + l] = o; }
        OUT4(xv0, 0,  0) OUT4(xv1, 1, 16) OUT4(xv2, 1, 32) OUT4(xv3, 2, 48)
#undef OUT4
    }
}

extern "C" void kernel_launch(void* const* d_in, const int* in_sizes, int n_in,
                              void* d_out, int out_size, void* d_ws, size_t ws_size,
                              hipStream_t stream) {
    const float* x = (const float*)d_in[0];
    const float* w = (const float*)d_in[1];
    const float* b = (const float*)d_in[2];
    float* out = (float*)d_out;
    const int n = in_sizes[0];
    const int nblk = n / 256;
    const int wgs = 2048;  // grid-stride; 2048 WGs x 4 waves x 4 blocks/wave
    hipLaunchKernelGGL(cliff_ln_kernel, dim3(wgs), dim3(256), 0, stream,
                       x, w, b, out, nblk);
}

// Round 2
// 126.198 us; speedup vs baseline: 1.6284x; 1.6284x over previous
//
#include <hip/hip_runtime.h>

// CliffordLayerNorm: per-256-float block, per-grade (popcount) layernorm.
// One wave handles 16 MV blocks (4 lanes each). Lane l (0..3) of a group
// holds the 64 elements m = 16k + 4l + j (k in 0..15, j in 0..3), i.e.
// float4 index 4k + l -> consecutive lanes read consecutive float4s.
// popcount(m) = pc(k) + pc(l) + pc(j): each lane's elements span relative
// grades 0..6 above base p = pc(l) in {0,1,2}. Per-grade sums are reduced
// with a 2-step "Pascal" butterfly over the 2 lane bits (arrays stay aligned
// to the grade base of the remaining unreduced bits, growing 7 -> 9).

static __device__ __forceinline__ float shx(float v, int m) {
    return __shfl_xor(v, m, 64);
}

// One pascal merge: combine lane-pairs differing in bit BM whose grade bases
// differ by 1.  b[j] = hi ? a[j-1] : a[j]  (a[-1]=a[L]=0), then
// a'[j] = b[j] + partner(b[j]).  Array length L -> L+1.
template <int BM, int L>
static __device__ __forceinline__ void pascal_step(float (&s)[9], float (&q)[9],
                                                   bool hi) {
#pragma unroll
    for (int j = L; j >= 0; --j) {
        float bs = (j == 0) ? (hi ? 0.0f : s[0])
                 : (j == L) ? (hi ? s[L - 1] : 0.0f)
                            : (hi ? s[j - 1] : s[j]);
        float bq = (j == 0) ? (hi ? 0.0f : q[0])
                 : (j == L) ? (hi ? q[L - 1] : 0.0f)
                            : (hi ? q[j - 1] : q[j]);
        s[j] = bs;  // safe: j descending, only j and j-1 of old array read
        q[j] = bq;
    }
#pragma unroll
    for (int j = 0; j <= L; ++j) {
        s[j] += shx(s[j], BM);
        q[j] += shx(q[j], BM);
    }
}

__global__ __launch_bounds__(256) void cliff_ln_kernel(
    const float* __restrict__ x, const float* __restrict__ w,
    const float* __restrict__ b, float* __restrict__ out, int nblk)
{
    const int lane = threadIdx.x & 63;
    const int grp  = lane >> 2;   // which of the 16 blocks this wave handles
    const int l    = lane & 3;    // lane within the 4-lane group
    const int p    = __popc(l);   // grade base of this lane's elements (0..2)
    const int wave_id     = (blockIdx.x * blockDim.x + threadIdx.x) >> 6;
    const int total_waves = (gridDim.x * blockDim.x) >> 6;

    // weight/bias are tiny and uniform: hoist
    float wg[9], bg[9];
#pragma unroll
    for (int g = 0; g < 9; ++g) { wg[g] = w[g]; bg[g] = b[g]; }

    const float invc[9] = {1.0f, 0.125f, 1.0f/28.0f, 1.0f/56.0f, 1.0f/70.0f,
                           1.0f/56.0f, 1.0f/28.0f, 0.125f, 1.0f};
    constexpr int PC[16] = {0,1,1,2,1,2,2,3,1,2,2,3,2,3,3,4};

    const int ntask = nblk >> 4;
    for (int task = wave_id; task < ntask; task += total_waves) {
        const int blk = (task << 4) + grp;
        const float4* xb = reinterpret_cast<const float4*>(x) + (size_t)blk * 64;

        float4 xv[16];
#pragma unroll
        for (int k = 0; k < 16; ++k) xv[k] = xb[4 * k + l];

        float s[9], q[9];
#pragma unroll
        for (int j = 0; j < 9; ++j) { s[j] = 0.0f; q[j] = 0.0f; }

        // relative grade = pc(k) + pc(j); pc over the float4 lanes = {0,1,1,2}
#define ACC1(v, r) { s[r] += (v); q[r] = fmaf((v), (v), q[r]); }
#pragma unroll
        for (int k = 0; k < 16; ++k) {
            const int r = PC[k];
            ACC1(xv[k].x, r + 0)
            ACC1(xv[k].y, r + 1)
            ACC1(xv[k].z, r + 1)
            ACC1(xv[k].w, r + 2)
        }
#undef ACC1

        const bool hi1 = (l & 1) != 0, hi2 = (l & 2) != 0;
        pascal_step<1, 7>(s, q, hi1);
        pascal_step<2, 8>(s, q, hi2);
        // s[g], q[g] = per-grade sum / sum-of-squares for this group's block

        float scl[9], sft[9];
#pragma unroll
        for (int g = 0; g < 9; ++g) {
            float mean = s[g] * invc[g];
            float var  = fmaf(-mean, mean, q[g] * invc[g]);
            var = fmaxf(var, 0.0f);
            float inv = rsqrtf(var + 1e-5f);
            float sc  = inv * wg[g];
            scl[g] = sc;
            sft[g] = fmaf(-mean, sc, bg[g]);
        }

        // shift arrays down by p (a[j] <- a[j+p]), p in 0..2, branchless;
        // only relative grades 0..6 are consumed below.
        const bool p2 = (p & 2) != 0, p1 = (p & 1) != 0;
#pragma unroll
        for (int j = 0; j < 7; ++j) { scl[j] = p2 ? scl[j+2] : scl[j];
                                      sft[j] = p2 ? sft[j+2] : sft[j]; }
#pragma unroll
        for (int j = 0; j < 7; ++j) { scl[j] = p1 ? scl[j+1] : scl[j];
                                      sft[j] = p1 ? sft[j+1] : sft[j]; }
        // scl[r]/sft[r] now correspond to absolute grade p + r

        float4* ob = reinterpret_cast<float4*>(out) + (size_t)blk * 64;
#pragma unroll
        for (int k = 0; k < 16; ++k) {
            const int r = PC[k];
            float4 o;
            o.x = fmaf(xv[k].x, scl[r + 0], sft[r + 0]);
            o.y = fmaf(xv[k].y, scl[r + 1], sft[r + 1]);
            o.z = fmaf(xv[k].z, scl[r + 1], sft[r + 1]);
            o.w = fmaf(xv[k].w, scl[r + 2], sft[r + 2]);
            ob[4 * k + l] = o;
        }
    }
}

extern "C" void kernel_launch(void* const* d_in, const int* in_sizes, int n_in,
                              void* d_out, int out_size, void* d_ws, size_t ws_size,
                              hipStream_t stream) {
    const float* x = (const float*)d_in[0];
    const float* w = (const float*)d_in[1];
    const float* b = (const float*)d_in[2];
    float* out = (float*)d_out;
    const int n = in_sizes[0];
    const int nblk = n / 256;
    // 16 blocks per wave; one wave-task per 16 blocks.
    const int ntask = nblk / 16;                     // 16384 for the bench shape
    int waves = ntask;
    int wgs = (waves + 3) / 4;                       // 4 waves per WG
    if (wgs > 8192) wgs = 8192;
    if (wgs < 1) wgs = 1;
    hipLaunchKernelGGL(cliff_ln_kernel, dim3(wgs), dim3(256), 0, stream,
                       x, w, b, out, nblk);
}

// Round 3
// 102.893 us; speedup vs baseline: 1.9972x; 1.2265x over previous
//
#include <hip/hip_runtime.h>

// CliffordLayerNorm: per-256-float block, per-grade (popcount) layernorm.
// One wave handles 16 MV blocks (4 lanes each). Lane l (0..3) of a group
// holds the 64 elements m = 16k + 4l + j (k in 0..15, j in 0..3).
// popcount(m) = pc(k) + pc(l) + pc(j): each lane's elements span relative
// grades 0..6 above base p = pc(l) in {0,1,2}. Per-grade sums reduced with a
// 2-step Pascal butterfly over the 2 lane bits (array grows 7 -> 9).
//
// Round-3 changes: (1) nontemporal stores so the 268 MB output stream does
// not evict x from the 256 MiB L3 (x then stays L3-resident across replays);
// (2) 2-task-per-wave software pipeline (A/B register buffers) so the next
// task's 16 global loads are in flight during the current task's compute.

typedef float f32x4 __attribute__((ext_vector_type(4)));

static __device__ __forceinline__ float shx(float v, int m) {
    return __shfl_xor(v, m, 64);
}

// Pascal merge over lane bit BM: b[j] = hi ? a[j-1] : a[j] (a[-1]=a[L]=0),
// then a'[j] = b[j] + partner(b[j]). Length L -> L+1.
template <int BM, int L>
static __device__ __forceinline__ void pascal_step(float (&s)[9], float (&q)[9],
                                                   bool hi) {
#pragma unroll
    for (int j = L; j >= 0; --j) {
        float bs = (j == 0) ? (hi ? 0.0f : s[0])
                 : (j == L) ? (hi ? s[L - 1] : 0.0f)
                            : (hi ? s[j - 1] : s[j]);
        float bq = (j == 0) ? (hi ? 0.0f : q[0])
                 : (j == L) ? (hi ? q[L - 1] : 0.0f)
                            : (hi ? q[j - 1] : q[j]);
        s[j] = bs;
        q[j] = bq;
    }
#pragma unroll
    for (int j = 0; j <= L; ++j) {
        s[j] += shx(s[j], BM);
        q[j] += shx(q[j], BM);
    }
}

__constant__ int PC_TBL[16] = {0,1,1,2,1,2,2,3,1,2,2,3,2,3,3,4};

static __device__ __forceinline__ void process_task(
    const f32x4 (&xv)[16], float* __restrict__ out, int blk, int l,
    bool p1, bool p2, bool hi1, bool hi2,
    const float (&wg)[9], const float (&bg)[9])
{
    constexpr int PC[16] = {0,1,1,2,1,2,2,3,1,2,2,3,2,3,3,4};
    const float invc[9] = {1.0f, 0.125f, 1.0f/28.0f, 1.0f/56.0f, 1.0f/70.0f,
                           1.0f/56.0f, 1.0f/28.0f, 0.125f, 1.0f};

    float s[9], q[9];
#pragma unroll
    for (int j = 0; j < 9; ++j) { s[j] = 0.0f; q[j] = 0.0f; }

#define ACC1(v, r) { s[r] += (v); q[r] = fmaf((v), (v), q[r]); }
#pragma unroll
    for (int k = 0; k < 16; ++k) {
        const int r = PC[k];
        ACC1(xv[k][0], r + 0)
        ACC1(xv[k][1], r + 1)
        ACC1(xv[k][2], r + 1)
        ACC1(xv[k][3], r + 2)
    }
#undef ACC1

    pascal_step<1, 7>(s, q, hi1);
    pascal_step<2, 8>(s, q, hi2);

    float scl[9], sft[9];
#pragma unroll
    for (int g = 0; g < 9; ++g) {
        float mean = s[g] * invc[g];
        float var  = fmaf(-mean, mean, q[g] * invc[g]);
        var = fmaxf(var, 0.0f);
        float inv = rsqrtf(var + 1e-5f);
        float sc  = inv * wg[g];
        scl[g] = sc;
        sft[g] = fmaf(-mean, sc, bg[g]);
    }

    // shift down by p = pc(l) in 0..2; only relative grades 0..6 consumed
#pragma unroll
    for (int j = 0; j < 7; ++j) { scl[j] = p2 ? scl[j+2] : scl[j];
                                  sft[j] = p2 ? sft[j+2] : sft[j]; }
#pragma unroll
    for (int j = 0; j < 7; ++j) { scl[j] = p1 ? scl[j+1] : scl[j];
                                  sft[j] = p1 ? sft[j+1] : sft[j]; }

    f32x4* ob = reinterpret_cast<f32x4*>(out) + (size_t)blk * 64;
#pragma unroll
    for (int k = 0; k < 16; ++k) {
        const int r = PC[k];
        f32x4 o;
        o[0] = fmaf(xv[k][0], scl[r + 0], sft[r + 0]);
        o[1] = fmaf(xv[k][1], scl[r + 1], sft[r + 1]);
        o[2] = fmaf(xv[k][2], scl[r + 1], sft[r + 1]);
        o[3] = fmaf(xv[k][3], scl[r + 2], sft[r + 2]);
        __builtin_nontemporal_store(o, &ob[4 * k + l]);
    }
}

__global__ __launch_bounds__(256) void cliff_ln_kernel(
    const float* __restrict__ x, const float* __restrict__ w,
    const float* __restrict__ b, float* __restrict__ out, int nblk)
{
    const int lane = threadIdx.x & 63;
    const int grp  = lane >> 2;
    const int l    = lane & 3;
    const int p    = __popc(l);
    const bool p1 = (p & 1) != 0, p2 = (p & 2) != 0;
    const bool hi1 = (l & 1) != 0, hi2 = (l & 2) != 0;
    const int wave_id     = (blockIdx.x * blockDim.x + threadIdx.x) >> 6;
    const int total_waves = (gridDim.x * blockDim.x) >> 6;

    float wg[9], bg[9];
#pragma unroll
    for (int g = 0; g < 9; ++g) { wg[g] = w[g]; bg[g] = b[g]; }

    const int ntask = nblk >> 4;
    int t = wave_id;
    if (t >= ntask) return;

#define LOADT(buf, task) { \
    const f32x4* xb = reinterpret_cast<const f32x4*>(x) + \
        ((size_t)(((task) << 4) + grp)) * 64; \
    _Pragma("unroll") \
    for (int k = 0; k < 16; ++k) buf[k] = xb[4 * k + l]; }

    f32x4 A[16], B[16];
    LOADT(A, t)
    while (true) {
        const int t2 = t + total_waves;
        const bool h2 = t2 < ntask;
        if (h2) LOADT(B, t2)
        process_task(A, out, (t << 4) + grp, l, p1, p2, hi1, hi2, wg, bg);
        if (!h2) break;
        const int t3 = t2 + total_waves;
        const bool h3 = t3 < ntask;
        if (h3) LOADT(A, t3)
        process_task(B, out, (t2 << 4) + grp, l, p1, p2, hi1, hi2, wg, bg);
        if (!h3) break;
        t = t3;
    }
#undef LOADT
}

extern "C" void kernel_launch(void* const* d_in, const int* in_sizes, int n_in,
                              void* d_out, int out_size, void* d_ws, size_t ws_size,
                              hipStream_t stream) {
    const float* x = (const float*)d_in[0];
    const float* w = (const float*)d_in[1];
    const float* b = (const float*)d_in[2];
    float* out = (float*)d_out;
    const int n = in_sizes[0];
    const int nblk = n / 256;
    const int ntask = nblk / 16;           // 16384 for the bench shape
    int waves = (ntask + 1) / 2;           // 2 tasks per wave
    int wgs = (waves + 3) / 4;             // 4 waves per WG -> 2048 WGs
    if (wgs > 8192) wgs = 8192;
    if (wgs < 1) wgs = 1;
    hipLaunchKernelGGL(cliff_ln_kernel, dim3(wgs), dim3(256), 0, stream,
                       x, w, b, out, nblk);
}